// Round 15
// baseline (157.216 us; speedup 1.0000x reference)
//
#include <hip/hip_runtime.h>
#include <hip/hip_fp16.h>

typedef _Float16 f16;
typedef _Float16 f16x8 __attribute__((ext_vector_type(8)));
typedef float f32x16 __attribute__((ext_vector_type(16)));

__device__ __forceinline__ f16x8 relu8(f16x8 a) {
#if __has_builtin(__builtin_elementwise_max)
  return __builtin_elementwise_max(a, (f16x8)(f16)0);   // v_pk_max_f16 x4
#else
  f16x8 r;
#pragma unroll
  for (int i = 0; i < 8; i++) r[i] = a[i] > (f16)0 ? a[i] : (f16)0;
  return r;
#endif
}

__device__ __forceinline__ f16x8 bcast8(f16 s) {
  return (f16x8){s, s, s, s, s, s, s, s};
}

// ---------------------------------------------------------------------------
// prep: B-fragments for mfma_f32_32x32x16_f16.
// frag fg = nh*128 + ng*64 + ks (ks = k-step of 16): lane l holds
// f16(W2[ks*16 + (l>>5)*8 + e][nh*64 + ng*32 + (l&31)]), e=0..7.
// nh slice = Wtp[nh*65536..] is 128 KB contiguous.
// ---------------------------------------------------------------------------
__global__ __launch_bounds__(256) void k_prep(const float* __restrict__ W2,
                                              f16* __restrict__ Wtp) {
  const int t = blockIdx.x * 256 + threadIdx.x;   // 16384 slots
  const int fg = t >> 6, l = t & 63;
  const int nh = fg >> 7, ng = (fg >> 6) & 1, ks = fg & 63;
  const int n = nh * 64 + ng * 32 + (l & 31);
  const int k0 = ks * 16 + (l >> 5) * 8;
  f16x8 o;
#pragma unroll
  for (int e = 0; e < 8; e++) o[e] = (f16)W2[(k0 + e) * 128 + n];
  *(f16x8*)(Wtp + fg * 512 + l * 8) = o;
}

// ---------------------------------------------------------------------------
// fused: 256 persistent blocks, 512 thr = 8 waves, 1 block/CU.
// 32x32x16 MFMA (R15: +15% rate, half the instr count of 16x16x32 ->
// less issue/phase-sync stall). Task = 8 i x 128 j x 64 n (one nh) x 1024 k;
// wave wv owns i = i0+wv, tile 4 jg(32 j) x 2 ng(32 n), acc 128 AGPR.
// Per K=32 iter: 8 ds_read_b128, 16 MFMA. No software prefetch (R12 lesson).
// Balanced task map (R14): 128 cheap diagonal tasks in slots {0..63,256..319}
// paired with complementary depth; 192 full tasks in {64..255}.
// A-frag: m=lane&31, k=(lane>>5)*8+e (analog of verified 16x16 layout).
// C/D: col(n)=lane&31, row(j)=(reg&3)+8*(reg>>2)+4*(lane>>5) [m74/m101].
// WRITE_SIZE ~1 MB is the no-spill canary.
// ---------------------------------------------------------------------------
__global__ __launch_bounds__(512, 2) void k_fused(
    const float* __restrict__ x, const float* __restrict__ W1,
    const float* __restrict__ b1, const float* __restrict__ b2,
    const float* __restrict__ W3, const float* __restrict__ b3,
    const f16* __restrict__ Wtp,
    float* __restrict__ Kp0, float* __restrict__ Kp1) {
  __shared__ f16 w2f[65536];                 // 128 KB: current nh's B-fragments
  __shared__ f16 w1af[1024], b1f[1024], w1bf[1024];
  __shared__ f16 hat[8192];                  // 16 KB: ha rows for task's 8 i
  __shared__ f16 xs[512];                    // f16(x)

  const int tid = threadIdx.x;
  const int lane = tid & 63, wv = tid >> 6;
  const int m32 = lane & 31, kh = lane >> 5; // MFMA lane coords (32-row, k-half)

  // --- one-time staging: W1 tables + f16(x)
  if (tid < 128) {
    const int c8 = tid << 3;
    const float4 a0 = *(const float4*)(W1 + c8);
    const float4 a1 = *(const float4*)(W1 + c8 + 4);
    const float4 g0 = *(const float4*)(b1 + c8);
    const float4 g1 = *(const float4*)(b1 + c8 + 4);
    f16x8 oa, og;
    oa[0] = (f16)a0.x; oa[1] = (f16)a0.y; oa[2] = (f16)a0.z; oa[3] = (f16)a0.w;
    oa[4] = (f16)a1.x; oa[5] = (f16)a1.y; oa[6] = (f16)a1.z; oa[7] = (f16)a1.w;
    og[0] = (f16)g0.x; og[1] = (f16)g0.y; og[2] = (f16)g0.z; og[3] = (f16)g0.w;
    og[4] = (f16)g1.x; og[5] = (f16)g1.y; og[6] = (f16)g1.z; og[7] = (f16)g1.w;
    *(f16x8*)(&w1af[c8]) = oa;
    *(f16x8*)(&b1f[c8]) = og;
  } else if (tid < 256) {
    const int c8 = (tid - 128) << 3;
    const float4 a0 = *(const float4*)(W1 + 1024 + c8);
    const float4 a1 = *(const float4*)(W1 + 1024 + c8 + 4);
    f16x8 ob;
    ob[0] = (f16)a0.x; ob[1] = (f16)a0.y; ob[2] = (f16)a0.z; ob[3] = (f16)a0.w;
    ob[4] = (f16)a1.x; ob[5] = (f16)a1.y; ob[6] = (f16)a1.z; ob[7] = (f16)a1.w;
    *(f16x8*)(&w1bf[c8]) = ob;
  } else if (tid < 320) {
    const int c8 = (tid - 256) << 3;
    const float4 x0 = *(const float4*)(x + c8);
    const float4 x1 = *(const float4*)(x + c8 + 4);
    f16x8 ox;
    ox[0] = (f16)x0.x; ox[1] = (f16)x0.y; ox[2] = (f16)x0.z; ox[3] = (f16)x0.w;
    ox[4] = (f16)x1.x; ox[5] = (f16)x1.y; ox[6] = (f16)x1.z; ox[7] = (f16)x1.w;
    *(f16x8*)(&xs[c8]) = ox;
  }

  int cur_nh = -1;

  for (int t = (int)blockIdx.x; t < 320; t += 256) {
    // --- task map (R14): cheap diagonal in {0..63, 256..319}, full in {64..255}
    int nh, jt, s;
    if (t < 64 || t >= 256) {
      const int b = (t < 64) ? t : (t - 256);
      nh = b & 1;
      const int jd = b >> 1;              // 0..31
      const int jt1 = jd >> 4, l = jd & 15;
      if (t < 64) { jt = jt1;            s = jt * 16 + l; }
      else        { jt = (jt1 + 2) & 3;  s = jt * 16 + (15 - l); }
    } else {
      const int f = t - 64;               // 0..191
      nh = f & 1;
      const int jf = f >> 1;              // 0..95
      if (jf < 16)      { jt = 1; s = jf; }
      else if (jf < 48) { jt = 2; s = jf - 16; }
      else              { jt = 3; s = jf - 48; }
    }
    const int i0 = s << 3, j0 = jt << 7;
    float* __restrict__ Kp = nh ? Kp1 : Kp0;

    __syncthreads();                  // prior task's LDS reads done; covers one-time staging
    if (nh != cur_nh) {               // stage this nh's W2 fragments (128 KB)
      const f16* src = Wtp + nh * 65536;
      #pragma unroll
      for (int p = 0; p < 16; p++) {
        const int off = p * 4096 + tid * 8;
        *(f16x8*)(&w2f[off]) = *(const f16x8*)(src + off);
      }
      cur_nh = nh;
    }
    {  // hat[il][k] = f16(x[i0+il]*W1a[k] + b1[k]); 512 thr x 16 f16
      const int il_s = tid >> 6, kb = (tid & 63) << 4;
      const f16x8 xv = bcast8(xs[i0 + il_s]);
      const f16x8 wa0 = *(const f16x8*)(&w1af[kb]);
      const f16x8 wa1 = *(const f16x8*)(&w1af[kb + 8]);
      const f16x8 bb0 = *(const f16x8*)(&b1f[kb]);
      const f16x8 bb1 = *(const f16x8*)(&b1f[kb + 8]);
      *(f16x8*)(&hat[il_s * 1024 + kb])     = xv * wa0 + bb0;
      *(f16x8*)(&hat[il_s * 1024 + kb + 8]) = xv * wa1 + bb1;
    }
    __syncthreads();

    const int i = i0 + wv;
    const int dij = i - j0;
    const int jgmin = (dij > 0) ? (dij >> 5) : 0;   // wave-uniform skip (32-j units)

    f16 xjs[4];
    #pragma unroll
    for (int jg = 0; jg < 4; jg++) xjs[jg] = xs[j0 + jg * 32 + m32];

    f32x16 acc[4][2];
    #pragma unroll
    for (int jg = 0; jg < 4; jg++)
      #pragma unroll
      for (int ng = 0; ng < 2; ng++)
        #pragma unroll
        for (int r = 0; r < 16; r++) acc[jg][ng][r] = 0.f;

    const f16* hrow  = hat + wv * 1024 + kh * 8;
    const f16* wrow  = w1bf + kh * 8;
    const f16* bbase = w2f + lane * 8;

    for (int ks2 = 0; ks2 < 32; ++ks2) {
      const int k0 = ks2 * 32;
      const f16x8 hv0 = *(const f16x8*)(hrow + k0);
      const f16x8 hv1 = *(const f16x8*)(hrow + k0 + 16);
      const f16x8 wb0 = *(const f16x8*)(wrow + k0);
      const f16x8 wb1 = *(const f16x8*)(wrow + k0 + 16);
      f16x8 bf[2][2];
      #pragma unroll
      for (int ng = 0; ng < 2; ng++)
        #pragma unroll
        for (int h = 0; h < 2; h++)
          bf[ng][h] = *(const f16x8*)(bbase + (ng * 64 + ks2 * 2 + h) * 512);
      #pragma unroll
      for (int jg = 0; jg < 4; jg++) {
        if (jg >= jgmin) {
          const f16x8 xjv = bcast8(xjs[jg]);
          const f16x8 af0 = relu8(xjv * wb0 + hv0);
          const f16x8 af1 = relu8(xjv * wb1 + hv1);
          #pragma unroll
          for (int ng = 0; ng < 2; ng++) {
            acc[jg][ng] = __builtin_amdgcn_mfma_f32_32x32x16_f16(af0, bf[ng][0], acc[jg][ng], 0, 0, 0);
            acc[jg][ng] = __builtin_amdgcn_mfma_f32_32x32x16_f16(af1, bf[ng][1], acc[jg][ng], 0, 0, 0);
          }
        }
      }
    }

    // --- epilogue: dot over this nh's 64 n; direct global writes (1 i/wave)
    float b2v[2], w3v[2];
    #pragma unroll
    for (int ng = 0; ng < 2; ng++) {
      const int n = nh * 64 + ng * 32 + m32;
      b2v[ng] = b2[n];
      w3v[ng] = W3[n];
    }
    const float badd = (nh == 0) ? b3[0] : 0.f;   // b3 added exactly once
    #pragma unroll
    for (int jg = 0; jg < 4; jg++) {
      if (jg >= jgmin) {
        #pragma unroll
        for (int r = 0; r < 16; r++) {
          float ssum = 0.f;
          #pragma unroll
          for (int ng = 0; ng < 2; ng++)
            ssum = fmaf(fmaxf(acc[jg][ng][r] + b2v[ng], 0.f), w3v[ng], ssum);
          ssum += __shfl_xor(ssum, 1, 64);
          ssum += __shfl_xor(ssum, 2, 64);
          ssum += __shfl_xor(ssum, 4, 64);
          ssum += __shfl_xor(ssum, 8, 64);
          ssum += __shfl_xor(ssum, 16, 64);
          if (m32 == 0) {
            const int row = (r & 3) + 8 * (r >> 2) + 4 * kh;  // C/D row [m74/m101]
            const int j = j0 + jg * 32 + row;
            if (j >= i) Kp[i * 512 + j] = ssum + badd;
          }
        }
      }
    }
  }
}

// ---------------------------------------------------------------------------
// atta: C = K^T K, K = Kp0 + Kp1 (summed on load). Below-diagonal entries
// UNWRITTEN -> masked to 0. Symmetry (pb<=qb + mirror), i-loop stops at pb+32.
// ---------------------------------------------------------------------------
__global__ __launch_bounds__(256) void k_atta(const float* __restrict__ K0,
                                              const float* __restrict__ K1,
                                              float* __restrict__ C) {
  const int pb = blockIdx.x * 32, qb = blockIdx.y * 32;
  if (pb > qb) return;
  __shared__ float sp[32][33], sq[32][33];
  const int tid = threadIdx.x;
  const int tx = tid & 15, ty = tid >> 4;
  float c00 = 0.f, c01 = 0.f, c10 = 0.f, c11 = 0.f;
  for (int i0 = 0; i0 < pb + 32; i0 += 32) {
    #pragma unroll
    for (int r = 0; r < 4; r++) {
      const int e = tid + 256 * r, ii = e >> 5, pp = e & 31;
      const int irow = i0 + ii;
      const int ip = irow * 512 + pb + pp, iq = irow * 512 + qb + pp;
      sp[ii][pp] = (irow <= pb + pp) ? K0[ip] + K1[ip] : 0.f;
      sq[ii][pp] = (irow <= qb + pp) ? K0[iq] + K1[iq] : 0.f;
    }
    __syncthreads();
    #pragma unroll 8
    for (int ii = 0; ii < 32; ii++) {
      const float a0 = sp[ii][ty * 2], a1 = sp[ii][ty * 2 + 1];
      const float b0 = sq[ii][tx * 2], b1 = sq[ii][tx * 2 + 1];
      c00 = fmaf(a0, b0, c00); c01 = fmaf(a0, b1, c01);
      c10 = fmaf(a1, b0, c10); c11 = fmaf(a1, b1, c11);
    }
    __syncthreads();
  }
  const int p0 = pb + ty * 2, q0 = qb + tx * 2;
  C[p0 * 512 + q0] = c00;       C[p0 * 512 + q0 + 1] = c01;
  C[(p0 + 1) * 512 + q0] = c10; C[(p0 + 1) * 512 + q0 + 1] = c11;
  C[q0 * 512 + p0] = c00;       C[(q0 + 1) * 512 + p0] = c01;
  C[q0 * 512 + p0 + 1] = c10;   C[(q0 + 1) * 512 + p0 + 1] = c11;
}

extern "C" void kernel_launch(void* const* d_in, const int* in_sizes, int n_in,
                              void* d_out, int out_size, void* d_ws, size_t ws_size,
                              hipStream_t stream) {
  const float* x  = (const float*)d_in[0];
  const float* W1 = (const float*)d_in[1];
  const float* b1 = (const float*)d_in[2];
  const float* W2 = (const float*)d_in[3];
  const float* b2 = (const float*)d_in[4];
  const float* W3 = (const float*)d_in[5];
  const float* b3 = (const float*)d_in[6];
  float* out = (float*)d_out;
  char* ws = (char*)d_ws;

  f16* Wtp = (f16*)ws;                              // 256 KB packed W2 B-fragments
  float* Kp0 = (float*)(ws + (256 << 10));          // 1 MB partial K (n 0..63)
  float* Kp1 = (float*)(ws + (256 << 10) + (1 << 20));  // 1 MB partial K (n 64..127)

  k_prep<<<64, 256, 0, stream>>>(W2, Wtp);
  k_fused<<<256, 512, 0, stream>>>(x, W1, b1, b2, W3, b3, Wtp, Kp0, Kp1);
  k_atta<<<dim3(16, 16), 256, 0, stream>>>(Kp0, Kp1, out);
}